// Round 8
// baseline (86.548 us; speedup 1.0000x reference)
//
#include <hip/hip_runtime.h>

// B=8, T=16, H=512, W=512
#define HH 512
#define WW 512
#define TT 16
#define NR 10         // staged img rows: clamp(ip-4 .. ip+5)  -> LDS = 20480 B exactly
#define OFF 4

typedef float vf4 __attribute__((ext_vector_type(4)));
typedef float vf2 __attribute__((ext_vector_type(2)));

__device__ __forceinline__ float warp_one(const float* __restrict__ lds_,
                                          const float* __restrict__ im,
                                          int ip, float fi, float fj,
                                          float ux, float uy) {
    float si = fi - ux;
    float sj = fj - uy;
    int i0 = (int)floorf(si);
    int j0 = (int)floorf(sj);
    i0 = min(max(i0, 0), HH - 1);
    j0 = min(max(j0, 0), WW - 1);
    int i1 = min(i0 + 1, HH - 1);
    int j1 = min(j0 + 1, WW - 1);
    // fractional weights from CLIPPED corners (matches reference)
    float di = si - (float)i0;
    float dj = sj - (float)j0;
    int s0 = i0 - ip + OFF;
    int s1 = i1 - ip + OFF;
    float f00, f01, f10, f11;
    if (((unsigned)s0 < NR) & ((unsigned)s1 < NR)) {
        // fast path: slot s holds img row clamp(ip-OFF+s) == i0/i1 (clipped),
        // so LDS content matches the clipped gather exactly.
        f00 = lds_[s0 * WW + j0];
        f01 = lds_[s0 * WW + j1];
        f10 = lds_[s1 * WW + j0];
        f11 = lds_[s1 * WW + j1];
    } else {
        // exactness fallback: direct global gather (P ~ 3e-5 per pixel)
        f00 = im[i0 * WW + j0];
        f01 = im[i0 * WW + j1];
        f10 = im[i1 * WW + j0];
        f11 = im[i1 * WW + j1];
    }
    float f0 = f00 + (f01 - f00) * dj;
    float f1 = f10 + (f11 - f10) * dj;
    return f0 + (f1 - f0) * di;
}

__global__ __launch_bounds__(256, 8) void SpatialWarp_kernel(
    const float* __restrict__ img,   // (B,H,W)
    const float* __restrict__ U,     // (B,T,H,W,2)
    float* __restrict__ out)         // (B,T,H,W)
{
    __shared__ float lds[NR * WW];             // 20480 B -> 8 blocks/CU

    int bid = blockIdx.x;                      // = b*256 + row-pair
    int b  = bid >> 8;
    int ip = (bid & 255) << 1;                 // base output row (even)
    const float* im = img + (size_t)b * (HH * WW);

    int k = threadIdx.x;                       // column-pair index 0..255
    int j = k << 1;
    float fj0 = (float)j, fj1 = (float)(j + 1);
    float fi0 = (float)ip, fi1 = (float)(ip + 1);

    size_t ubase = (((size_t)b * TT) * HH + ip) * (WW / 2);  // float4 units, t=0
    const vf4* Uv = reinterpret_cast<const vf4*>(U);

    // prologue: t=0 U for both rows (overlaps staging) — plain loads (no nt)
    vf4 u0c = Uv[ubase + k];
    vf4 u1c = Uv[ubase + (WW / 2) + k];

    // stage img rows clamp(ip-OFF .. ip-OFF+NR-1) into LDS (vec4, coalesced)
    for (int idx = threadIdx.x; idx < NR * (WW / 4); idx += 256) {
        int s = idx >> 7;            // / 128 vf4-per-row
        int c = idx & 127;
        int r = min(max(ip - OFF + s, 0), HH - 1);
        reinterpret_cast<vf4*>(lds)[idx] =
            reinterpret_cast<const vf4*>(im + (size_t)r * WW)[c];
    }
    __syncthreads();

#pragma unroll
    for (int t = 0; t < TT; ++t) {
        vf4 u0n, u1n;
        if (t < TT - 1) {
            size_t un = ubase + (size_t)(t + 1) * HH * (WW / 2);
            u0n = Uv[un + k];
            u1n = Uv[un + (WW / 2) + k];
        }
        float r00 = warp_one(lds, im, ip, fi0, fj0, u0c.x, u0c.y);
        float r01 = warp_one(lds, im, ip, fi0, fj1, u0c.z, u0c.w);
        float r10 = warp_one(lds, im, ip, fi1, fj0, u1c.x, u1c.y);
        float r11 = warp_one(lds, im, ip, fi1, fj1, u1c.z, u1c.w);

        size_t obase = (((size_t)b * TT + t) * HH + ip) * WW;
        vf2 rv0; rv0.x = r00; rv0.y = r01;
        vf2 rv1; rv1.x = r10; rv1.y = r11;
        reinterpret_cast<vf2*>(out + obase)[k] = rv0;        // plain stores (no nt)
        reinterpret_cast<vf2*>(out + obase + WW)[k] = rv1;

        u0c = u0n; u1c = u1n;
    }
}

extern "C" void kernel_launch(void* const* d_in, const int* in_sizes, int n_in,
                              void* d_out, int out_size, void* d_ws, size_t ws_size,
                              hipStream_t stream) {
    const float* img = (const float*)d_in[0];   // (8,512,512) fp32
    const float* U   = (const float*)d_in[1];   // (8,16,512,512,2) fp32
    float* out = (float*)d_out;                 // (8,16,512,512) fp32

    dim3 block(256);
    dim3 grid(8 * (HH / 2));                    // 2048 blocks: one per (b, row-pair)
    hipLaunchKernelGGL(SpatialWarp_kernel, grid, block, 0, stream,
                       img, U, out);
}

// Round 9
// 79.573 us; speedup vs baseline: 1.0877x; 1.0877x over previous
//
#include <hip/hip_runtime.h>

// B=8, T=16, H=512, W=512
#define HH 512
#define WW 512
#define TT 16
#define NR 10         // staged img rows: clamp(ip-4 .. ip+5)  -> LDS = 20480 B exactly
#define OFF 4

typedef float vf4 __attribute__((ext_vector_type(4)));
typedef float vf2 __attribute__((ext_vector_type(2)));

__device__ __forceinline__ float warp_one(const float* __restrict__ lds_,
                                          const float* __restrict__ im,
                                          int ip, float fi, float fj,
                                          float ux, float uy) {
    float si = fi - ux;
    float sj = fj - uy;
    int i0 = (int)floorf(si);
    int j0 = (int)floorf(sj);
    i0 = min(max(i0, 0), HH - 1);
    j0 = min(max(j0, 0), WW - 1);
    int i1 = min(i0 + 1, HH - 1);
    int j1 = min(j0 + 1, WW - 1);
    // fractional weights from CLIPPED corners (matches reference)
    float di = si - (float)i0;
    float dj = sj - (float)j0;
    int s0 = i0 - ip + OFF;
    int s1 = i1 - ip + OFF;
    float f00, f01, f10, f11;
    if (((unsigned)s0 < NR) & ((unsigned)s1 < NR)) {
        // fast path: slot s holds img row clamp(ip-OFF+s) == i0/i1 (clipped),
        // so LDS content matches the clipped gather exactly.
        f00 = lds_[s0 * WW + j0];
        f01 = lds_[s0 * WW + j1];
        f10 = lds_[s1 * WW + j0];
        f11 = lds_[s1 * WW + j1];
    } else {
        // exactness fallback: direct global gather (P ~ 3e-5 per pixel)
        f00 = im[i0 * WW + j0];
        f01 = im[i0 * WW + j1];
        f10 = im[i1 * WW + j0];
        f11 = im[i1 * WW + j1];
    }
    float f0 = f00 + (f01 - f00) * dj;
    float f1 = f10 + (f11 - f10) * dj;
    return f0 + (f1 - f0) * di;
}

__global__ __launch_bounds__(256, 8) void SpatialWarp_kernel(
    const float* __restrict__ img,   // (B,H,W)
    const float* __restrict__ U,     // (B,T,H,W,2)
    float* __restrict__ out)         // (B,T,H,W)
{
    __shared__ float lds[NR * WW];             // 20480 B -> 8 blocks/CU

    int bid = blockIdx.x;                      // = b*256 + row-pair
    int b  = bid >> 8;
    int ip = (bid & 255) << 1;                 // base output row (even)
    const float* im = img + (size_t)b * (HH * WW);

    int k = threadIdx.x;                       // column-pair index 0..255
    int j = k << 1;
    float fj0 = (float)j, fj1 = (float)(j + 1);
    float fi0 = (float)ip, fi1 = (float)(ip + 1);

    size_t ubase = (((size_t)b * TT) * HH + ip) * (WW / 2);  // float4 units, t=0
    size_t ustep = (size_t)HH * (WW / 2);                    // per-t stride
    const vf4* Uv = reinterpret_cast<const vf4*>(U);

    // depth-2 software pipeline: slots t%3; prologue loads t=0 and t=1
    vf4 ua[3], ub[3];
    ua[0] = __builtin_nontemporal_load(Uv + ubase + k);
    ub[0] = __builtin_nontemporal_load(Uv + ubase + (WW / 2) + k);
    ua[1] = __builtin_nontemporal_load(Uv + ubase + ustep + k);
    ub[1] = __builtin_nontemporal_load(Uv + ubase + ustep + (WW / 2) + k);

    // stage img rows clamp(ip-OFF .. ip-OFF+NR-1) into LDS (vec4, coalesced)
    for (int idx = threadIdx.x; idx < NR * (WW / 4); idx += 256) {
        int s = idx >> 7;            // / 128 vf4-per-row
        int c = idx & 127;
        int r = min(max(ip - OFF + s, 0), HH - 1);
        reinterpret_cast<vf4*>(lds)[idx] =
            reinterpret_cast<const vf4*>(im + (size_t)r * WW)[c];
    }
    __syncthreads();

#pragma unroll
    for (int t = 0; t < TT; ++t) {
        if (t + 2 < TT) {
            size_t un = ubase + (size_t)(t + 2) * ustep;
            ua[(t + 2) % 3] = __builtin_nontemporal_load(Uv + un + k);
            ub[(t + 2) % 3] = __builtin_nontemporal_load(Uv + un + (WW / 2) + k);
        }
        vf4 u0c = ua[t % 3];
        vf4 u1c = ub[t % 3];
        float r00 = warp_one(lds, im, ip, fi0, fj0, u0c.x, u0c.y);
        float r01 = warp_one(lds, im, ip, fi0, fj1, u0c.z, u0c.w);
        float r10 = warp_one(lds, im, ip, fi1, fj0, u1c.x, u1c.y);
        float r11 = warp_one(lds, im, ip, fi1, fj1, u1c.z, u1c.w);

        size_t obase = (((size_t)b * TT + t) * HH + ip) * WW;
        vf2 rv0; rv0.x = r00; rv0.y = r01;
        vf2 rv1; rv1.x = r10; rv1.y = r11;
        __builtin_nontemporal_store(rv0, reinterpret_cast<vf2*>(out + obase) + k);
        __builtin_nontemporal_store(rv1, reinterpret_cast<vf2*>(out + obase + WW) + k);
    }
}

extern "C" void kernel_launch(void* const* d_in, const int* in_sizes, int n_in,
                              void* d_out, int out_size, void* d_ws, size_t ws_size,
                              hipStream_t stream) {
    const float* img = (const float*)d_in[0];   // (8,512,512) fp32
    const float* U   = (const float*)d_in[1];   // (8,16,512,512,2) fp32
    float* out = (float*)d_out;                 // (8,16,512,512) fp32

    dim3 block(256);
    dim3 grid(8 * (HH / 2));                    // 2048 blocks: one per (b, row-pair)
    hipLaunchKernelGGL(SpatialWarp_kernel, grid, block, 0, stream,
                       img, U, out);
}